// Round 6
// baseline (203.033 us; speedup 1.0000x reference)
//
#include <hip/hip_runtime.h>
#include <hip/hip_fp16.h>

#define POOLED 7
#define RATIO 2

constexpr int C_ = 256;
constexpr int H_ = 192;
constexpr int W_ = 192;
constexpr int P_ = H_ * W_;           // pixels per plane
constexpr int PP2 = POOLED * POOLED;  // 49

// ---------------- NCHW fp32 -> NHWC fp16 transpose -------------------------
constexpr int TC = 32;
constexpr int TP = 128;
constexpr int TPAD = TP + 1;

__global__ __launch_bounds__(256)
void nchw_to_nhwc_h(const float* __restrict__ in, __half* __restrict__ outT) {
    __shared__ float tile[TC][TPAD];
    const int b  = blockIdx.z;
    const int p0 = blockIdx.x * TP;
    const int c0 = blockIdx.y * TC;
    const float* src = in   + (size_t)b * C_ * P_;
    __half*      dst = outT + (size_t)b * P_ * C_;

    const int t = threadIdx.x;

    #pragma unroll
    for (int k = 0; k < 4; ++k) {
        const int q  = t + 256 * k;
        const int c  = q >> 5;
        const int pv = q & 31;
        const float4 v = *(const float4*)&src[(size_t)(c0 + c) * P_ + p0 + 4 * pv];
        tile[c][4 * pv + 0] = v.x;
        tile[c][4 * pv + 1] = v.y;
        tile[c][4 * pv + 2] = v.z;
        tile[c][4 * pv + 3] = v.w;
    }
    __syncthreads();

    #pragma unroll
    for (int k = 0; k < 2; ++k) {
        const int q  = t + 256 * k;
        const int p  = q >> 2;
        const int c8 = (q & 3) * 8;
        union { __half h[8]; float4 f; } u;
        #pragma unroll
        for (int i = 0; i < 8; ++i) u.h[i] = __float2half(tile[c8 + i][p]);
        *(float4*)&dst[(size_t)(p0 + p) * C_ + c0 + c8] = u.f;
    }
}

// ---------------- RoIAlign on NHWC fp16 ------------------------------------
// Round-6: request-volume theory. 5 structures (loads/bin 2..16, divergent &
// coalesced, VGPR 64/128 budgets, L2-resident & not) all land 44-49 us ->
// per-CU gather service pinned ~0.12 lines/cy regardless of concurrency and
// hit tier. Surviving lever: issue FEWER requests. Corners form a cross
// product {rows}x{cols}; per bin-row stage <=4 distinct rows x Cx dedup'd
// cols into LDS ONCE (each record = one coalesced 64-dword wave-load,
// batched x8), then all 7 bins read LDS. Request volume ~0.75x average.
constexpr int CB  = 128;              // channels per block
constexpr int BPR = C_ / CB;          // 2 blocks per ROI
constexpr int BST = CB + 2;           // 130 halves

__global__ __launch_bounds__(256, 4)
void roi_align_nhwc_h(const float* __restrict__ rois,
                      const __half* __restrict__ featT,   // (B,H,W,C) fp16
                      const int* __restrict__ stride_ptr,
                      float* __restrict__ out, int N) {
    __shared__ __half lds_out[PP2 * BST];  // 12740 B
    __shared__ int4 coord[28];             // [0..13]=y {lo*W, hi*W, frac*0.5, valid}
                                           // [14..27]=x {lo, hi, frac*0.5, valid}
    __shared__ uint stage[4][28][64];      // 28672 B: 4 row-slots x 28 cols x 256B
    __shared__ int  xcol[28];              // dedup'd pixel-x list
    __shared__ int2 xidx[14];              // per x-sample: (lo idx, hi idx) into xcol
    __shared__ int  CxS;

    const int blk  = blockIdx.x;
    const int n    = blk >> 1;           // ROI index
    const int ch0  = (blk & 1) * CB;     // channel half
    const int t    = threadIdx.x;
    const int lane = t & 63;
    const int wave = t >> 6;             // 0..3

    const float scale = 1.0f / (float)stride_ptr[0];
    const float* r = rois + (size_t)n * 5;
    const int   b   = (int)r[0];
    const float rx1 = r[1] * scale;
    const float ry1 = r[2] * scale;
    const float rx2 = r[3] * scale;
    const float ry2 = r[4] * scale;
    const float bin_w = fmaxf(rx2 - rx1, 1.0f) * (1.0f / (float)POOLED);
    const float bin_h = fmaxf(ry2 - ry1, 1.0f) * (1.0f / (float)POOLED);

    if (t < 28) {
        const bool  isY   = t < 14;
        const int   s     = isY ? t : t - 14;
        const float start = isY ? ry1 : rx1;
        const float bsz   = isY ? bin_h : bin_w;
        const int   size  = isY ? H_ : W_;
        const float cc0   = start + ((float)s + 0.5f) * 0.5f * bsz;
        const bool  valid = (cc0 > -1.0f) && (cc0 < (float)size);
        float cc = fminf(fmaxf(cc0, 0.0f), (float)(size - 1));
        int lo = (int)floorf(cc);
        if (lo > size - 1) lo = size - 1;
        const int hi = min(lo + 1, size - 1);
        const float frac = (cc - (float)lo) * 0.5f;   // fold mean/4 (x*y halves)
        int4 e;
        e.x = isY ? lo * W_ : lo;
        e.y = isY ? hi * W_ : hi;
        e.z = __float_as_int(frac);
        e.w = valid ? 1 : 0;
        coord[t] = e;
    }
    __syncthreads();

    // Build dedup'd column list (x positions monotone non-decreasing in s).
    if (t == 0) {
        int cnt = 0, vA = -1000000, vB = -1000000, iA = 0, iB = 0;
        for (int s = 0; s < 14; ++s) {
            const int c0 = coord[14 + s].x;
            const int c1 = coord[14 + s].y;   // c1 in {c0, c0+1}
            int i0, i1;
            if (c0 == vA)      i0 = iA;
            else if (c0 == vB) i0 = iB;
            else { xcol[cnt] = c0; i0 = cnt++; }
            if (c1 == c0)      i1 = i0;
            else if (c1 == vB) i1 = iB;
            else { xcol[cnt] = c1; i1 = cnt++; }
            vA = c0; iA = i0; vB = c1; iB = i1;
            xidx[s] = make_int2(i0, i1);
        }
        CxS = cnt;   // <= 28
    }
    __syncthreads();

    const int Cx = CxS;
    // dword index of this lane's channel pair within a pixel's 512B record
    const uint* fb = (const uint*)featT + (size_t)b * P_ * (C_ / 2) + (ch0 >> 1);

    for (int ph = 0; ph < POOLED; ++ph) {
        const int4 cyA = coord[2 * ph + 0];   // y-sample 0 of this bin-row
        const int4 cyB = coord[2 * ph + 1];   // y-sample 1
        const int R0 = cyA.x, R1 = cyA.y, R2 = cyB.x, R3 = cyB.y;  // rows*W
        // slot dedup remap (computed redundantly per thread, registers only)
        const int rm1 = (R1 == R0) ? 0 : 1;
        const int rm2 = (R2 == R0) ? 0 : (R2 == R1) ? rm1 : 2;
        const int rm3 = (R3 == R0) ? 0 : (R3 == R1) ? rm1 : (R3 == R2) ? rm2 : 3;

        // ---- stage phase: wave w loads row-slot w (skip duplicate slots) ----
        const int  myR     = (wave == 0) ? R0 : (wave == 1) ? R1
                           : (wave == 2) ? R2 : R3;
        const bool doStage = (wave == 0) || (wave == 1 ? (rm1 == 1)
                           : wave == 2 ? (rm2 == 2) : (rm3 == 3));
        if (doStage) {
            for (int c = 0; c < Cx; c += 8) {     // 8-deep batches, clamped tail
                int  cj[8];
                uint v[8];
                #pragma unroll
                for (int j = 0; j < 8; ++j) {
                    cj[j] = min(c + j, Cx - 1);
                    v[j]  = fb[(size_t)(myR + xcol[cj[j]]) * (C_ / 2) + lane];
                }
                #pragma unroll
                for (int j = 0; j < 8; ++j)
                    stage[wave][cj[j]][lane] = v[j];   // dup writes: same data
            }
        }
        __syncthreads();

        // ---- compute phase: bins pw = wave, wave+4 of this bin-row ----------
        for (int pw = wave; pw < POOLED; pw += 4) {
            const int bin = ph * POOLED + pw;
            const int4 cx0 = coord[14 + 2 * pw + 0];
            const int4 cx1 = coord[14 + 2 * pw + 1];
            const int2 xiA = xidx[2 * pw + 0];
            const int2 xiB = xidx[2 * pw + 1];

            const float fy0 = __int_as_float(cyA.z);
            const float fy1 = __int_as_float(cyB.z);
            const float fx0 = __int_as_float(cx0.z);
            const float fx1 = __int_as_float(cx1.z);

            const float m00 = (cyA.w & cx0.w) ? 1.0f : 0.0f;
            const float m01 = (cyA.w & cx1.w) ? 1.0f : 0.0f;
            const float m10 = (cyB.w & cx0.w) ? 1.0f : 0.0f;
            const float m11 = (cyB.w & cx1.w) ? 1.0f : 0.0f;

            const float wyl0 = 0.5f - fy0, wyh0 = fy0;   // 0.5-scaled bases
            const float wyl1 = 0.5f - fy1, wyh1 = fy1;
            const float wxl0 = 0.5f - fx0, wxh0 = fx0;
            const float wxl1 = 0.5f - fx1, wxh1 = fx1;

            uint  u[16];
            float wgt[16];
            // sample (y0,x0): rows slots (0, rm1) x cols (xiA.x, xiA.y)
            u[ 0] = stage[0  ][xiA.x][lane];  wgt[ 0] = wyl0 * wxl0 * m00;
            u[ 1] = stage[0  ][xiA.y][lane];  wgt[ 1] = wyl0 * wxh0 * m00;
            u[ 2] = stage[rm1][xiA.x][lane];  wgt[ 2] = wyh0 * wxl0 * m00;
            u[ 3] = stage[rm1][xiA.y][lane];  wgt[ 3] = wyh0 * wxh0 * m00;
            // sample (y0,x1)
            u[ 4] = stage[0  ][xiB.x][lane];  wgt[ 4] = wyl0 * wxl1 * m01;
            u[ 5] = stage[0  ][xiB.y][lane];  wgt[ 5] = wyl0 * wxh1 * m01;
            u[ 6] = stage[rm1][xiB.x][lane];  wgt[ 6] = wyh0 * wxl1 * m01;
            u[ 7] = stage[rm1][xiB.y][lane];  wgt[ 7] = wyh0 * wxh1 * m01;
            // sample (y1,x0): rows slots (rm2, rm3)
            u[ 8] = stage[rm2][xiA.x][lane];  wgt[ 8] = wyl1 * wxl0 * m10;
            u[ 9] = stage[rm2][xiA.y][lane];  wgt[ 9] = wyl1 * wxh0 * m10;
            u[10] = stage[rm3][xiA.x][lane];  wgt[10] = wyh1 * wxl0 * m10;
            u[11] = stage[rm3][xiA.y][lane];  wgt[11] = wyh1 * wxh0 * m10;
            // sample (y1,x1)
            u[12] = stage[rm2][xiB.x][lane];  wgt[12] = wyl1 * wxl1 * m11;
            u[13] = stage[rm2][xiB.y][lane];  wgt[13] = wyl1 * wxh1 * m11;
            u[14] = stage[rm3][xiB.x][lane];  wgt[14] = wyh1 * wxl1 * m11;
            u[15] = stage[rm3][xiB.y][lane];  wgt[15] = wyh1 * wxh1 * m11;

            __half2 acc = __float2half2_rn(0.f);
            #pragma unroll
            for (int k = 0; k < 16; ++k)
                acc = __hfma2(__float2half2_rn(wgt[k]),
                              *(const __half2*)&u[k], acc);

            *(__half2*)&lds_out[bin * BST + 2 * lane] = acc;
        }
        __syncthreads();   // protect stage[] before next bin-row overwrites
    }

    // Contiguous 128*49-float output slice: out + n*12544 + ch0*49.
    float* obase = out + (size_t)n * (C_ * PP2) + (size_t)ch0 * PP2;
    float4* o4 = (float4*)obase;
    for (int i = t; i < (CB * PP2) / 4; i += 256) {   // 1568 float4
        const int l0 = i * 4;
        float4 v;
        #pragma unroll
        for (int j = 0; j < 4; ++j) {
            const int l  = l0 + j;
            const int c  = l / PP2;          // local channel 0..127
            const int bn = l - c * PP2;
            ((float*)&v)[j] = __half2float(lds_out[bn * BST + c]);
        }
        o4[i] = v;
    }
}

// ---------------- Fallback (NCHW direct, fp32) ------------------------------
__global__ __launch_bounds__(256)
void roi_align_kernel(const float* __restrict__ rois,
                      const float* __restrict__ feat,
                      const int* __restrict__ stride_ptr,
                      int B, int C, int H, int W, int N,
                      float* __restrict__ out) {
    const int total = N * C * POOLED * POOLED;
    int idx = blockIdx.x * blockDim.x + threadIdx.x;
    if (idx >= total) return;

    const float scale = 1.0f / (float)stride_ptr[0];

    int pw = idx % POOLED;
    int ph = (idx / POOLED) % POOLED;
    int c  = (idx / (POOLED * POOLED)) % C;
    int n  = idx / (POOLED * POOLED * C);

    const float* r = rois + (size_t)n * 5;
    int b = (int)r[0];
    float x1 = r[1] * scale;
    float y1 = r[2] * scale;
    float x2 = r[3] * scale;
    float y2 = r[4] * scale;
    float bin_w = fmaxf(x2 - x1, 1.0f) / (float)POOLED;
    float bin_h = fmaxf(y2 - y1, 1.0f) / (float)POOLED;

    const float* plane = feat + ((size_t)b * C + c) * (size_t)(H * W);

    float acc = 0.0f;
    #pragma unroll
    for (int sy = 0; sy < RATIO; ++sy) {
        float iy = ((float)(ph * RATIO + sy) + 0.5f) / (float)RATIO;
        float yy = y1 + iy * bin_h;
        bool vy = (yy > -1.0f) && (yy < (float)H);
        float cy = fminf(fmaxf(yy, 0.0f), (float)(H - 1));
        int y0 = (int)floorf(cy);
        if (y0 > H - 1) y0 = H - 1;
        int y1i = min(y0 + 1, H - 1);
        float fy = cy - (float)y0;
        float hy = 1.0f - fy;

        #pragma unroll
        for (int sx = 0; sx < RATIO; ++sx) {
            float ix = ((float)(pw * RATIO + sx) + 0.5f) / (float)RATIO;
            float xx = x1 + ix * bin_w;
            bool vx = (xx > -1.0f) && (xx < (float)W);
            if (!(vy && vx)) continue;
            float cx = fminf(fmaxf(xx, 0.0f), (float)(W - 1));
            int x0 = (int)floorf(cx);
            if (x0 > W - 1) x0 = W - 1;
            int x1i = min(x0 + 1, W - 1);
            float fx = cx - (float)x0;
            float hx = 1.0f - fx;

            float v00 = plane[y0  * W + x0 ];
            float v01 = plane[y0  * W + x1i];
            float v10 = plane[y1i * W + x0 ];
            float v11 = plane[y1i * W + x1i];

            acc += hy * hx * v00 + hy * fx * v01 + fy * hx * v10 + fy * fx * v11;
        }
    }

    out[idx] = acc * 0.25f;
}

extern "C" void kernel_launch(void* const* d_in, const int* in_sizes, int n_in,
                              void* d_out, int out_size, void* d_ws, size_t ws_size,
                              hipStream_t stream) {
    const float* rois = (const float*)d_in[0];
    const float* feat = (const float*)d_in[1];
    const int* stride_ptr = (const int*)d_in[2];

    const int N = in_sizes[0] / 5;
    const int B = in_sizes[1] / (C_ * P_);
    float* out = (float*)d_out;

    const size_t need = (size_t)B * P_ * C_ * sizeof(__half);
    if (ws_size >= need) {
        __half* featT = (__half*)d_ws;
        dim3 tgrid(P_ / TP, C_ / TC, B);
        nchw_to_nhwc_h<<<tgrid, 256, 0, stream>>>(feat, featT);

        roi_align_nhwc_h<<<N * BPR, 256, 0, stream>>>(rois, featT, stride_ptr,
                                                      out, N);
    } else {
        const int total = N * C_ * POOLED * POOLED;
        const int block = 256;
        const int grid = (total + block - 1) / block;
        roi_align_kernel<<<grid, block, 0, stream>>>(rois, feat, stride_ptr,
                                                     B, C_, H_, W_, N, out);
    }
}

// Round 7
// 192.271 us; speedup vs baseline: 1.0560x; 1.0560x over previous
//
#include <hip/hip_runtime.h>
#include <hip/hip_fp16.h>

#define POOLED 7
#define RATIO 2

constexpr int C_ = 256;
constexpr int H_ = 192;
constexpr int W_ = 192;
constexpr int P_ = H_ * W_;           // pixels per plane
constexpr int PP2 = POOLED * POOLED;  // 49

// ---------------- NCHW fp32 -> NHWC fp16 transpose -------------------------
constexpr int TC = 32;
constexpr int TP = 128;
constexpr int TPAD = TP + 1;

__global__ __launch_bounds__(256)
void nchw_to_nhwc_h(const float* __restrict__ in, __half* __restrict__ outT) {
    __shared__ float tile[TC][TPAD];
    const int b  = blockIdx.z;
    const int p0 = blockIdx.x * TP;
    const int c0 = blockIdx.y * TC;
    const float* src = in   + (size_t)b * C_ * P_;
    __half*      dst = outT + (size_t)b * P_ * C_;

    const int t = threadIdx.x;

    #pragma unroll
    for (int k = 0; k < 4; ++k) {
        const int q  = t + 256 * k;
        const int c  = q >> 5;
        const int pv = q & 31;
        const float4 v = *(const float4*)&src[(size_t)(c0 + c) * P_ + p0 + 4 * pv];
        tile[c][4 * pv + 0] = v.x;
        tile[c][4 * pv + 1] = v.y;
        tile[c][4 * pv + 2] = v.z;
        tile[c][4 * pv + 3] = v.w;
    }
    __syncthreads();

    #pragma unroll
    for (int k = 0; k < 2; ++k) {
        const int q  = t + 256 * k;
        const int p  = q >> 2;
        const int c8 = (q & 3) * 8;
        union { __half h[8]; float4 f; } u;
        #pragma unroll
        for (int i = 0; i < 8; ++i) u.h[i] = __float2half(tile[c8 + i][p]);
        *(float4*)&dst[(size_t)(p0 + p) * C_ + c0 + c8] = u.f;
    }
}

// ---------------- RoIAlign on NHWC fp16 ------------------------------------
// Round-7: line-service/MSHR theory. Across rounds 0-5, request count swept
// 392..1568 per ROI at CONSTANT ~3136 lines/ROI and constant 44-47 us ->
// bound is lines delivered per CU (~0.11 lines/cy ~= 32 outstanding misses
// x ~300cy L2 latency = L1/TCP miss-slot cap), not requests, not VGPR-level
// MLP, not hit tier (R3), not occupancy. R6's LDS-dedup paid 2x in
// serialization -> reverted to R5 structure (best, ~44 us).
// ONE change vs R5: the 16 gathers are __builtin_nontemporal_load (nt bit,
// L1-bypass path) -> should not consume L1 miss-tracking slots. Zero reuse
// lost (271 KB footprint vs 32 KB L1).
constexpr int CB  = 128;              // channels per block
constexpr int BPR = C_ / CB;          // 2 blocks per ROI
constexpr int BST = CB + 2;           // 130 halves

__global__ __launch_bounds__(256, 4)
void roi_align_nhwc_h(const float* __restrict__ rois,
                      const __half* __restrict__ featT,   // (B,H,W,C) fp16
                      const int* __restrict__ stride_ptr,
                      float* __restrict__ out, int N) {
    __shared__ __half lds_out[PP2 * BST];  // 12740 B
    __shared__ int4 coord[28];             // [0..13]=y {lo*W, hi*W, frac*0.5, valid}
                                           // [14..27]=x {lo, hi, frac*0.5, valid}

    const int blk  = blockIdx.x;
    const int n    = blk >> 1;           // ROI index
    const int ch0  = (blk & 1) * CB;     // channel half
    const int t    = threadIdx.x;
    const int lane = t & 63;
    const int wave = t >> 6;             // 0..3

    const float scale = 1.0f / (float)stride_ptr[0];
    const float* r = rois + (size_t)n * 5;
    const int   b   = (int)r[0];
    const float rx1 = r[1] * scale;
    const float ry1 = r[2] * scale;
    const float rx2 = r[3] * scale;
    const float ry2 = r[4] * scale;
    const float bin_w = fmaxf(rx2 - rx1, 1.0f) * (1.0f / (float)POOLED);
    const float bin_h = fmaxf(ry2 - ry1, 1.0f) * (1.0f / (float)POOLED);

    if (t < 28) {
        const bool  isY   = t < 14;
        const int   s     = isY ? t : t - 14;
        const float start = isY ? ry1 : rx1;
        const float bsz   = isY ? bin_h : bin_w;
        const int   size  = isY ? H_ : W_;
        const float cc0   = start + ((float)s + 0.5f) * 0.5f * bsz;
        const bool  valid = (cc0 > -1.0f) && (cc0 < (float)size);
        float cc = fminf(fmaxf(cc0, 0.0f), (float)(size - 1));
        int lo = (int)floorf(cc);
        if (lo > size - 1) lo = size - 1;
        const int hi = min(lo + 1, size - 1);
        const float frac = (cc - (float)lo) * 0.5f;   // fold mean/4 (x*y halves)
        int4 e;
        e.x = isY ? lo * W_ : lo;
        e.y = isY ? hi * W_ : hi;
        e.z = __float_as_int(frac);
        e.w = valid ? 1 : 0;
        coord[t] = e;
    }
    __syncthreads();

    // lane's dword (= half2 = 2 channels) within each pixel's 512B record
    const uint* fb = (const uint*)featT + (size_t)b * P_ * (C_ / 2)
                                        + (ch0 >> 1) + lane;

    const int bin_lo = (wave * PP2) >> 2;         // 0,12,24,36
    const int bin_hi = ((wave + 1) * PP2) >> 2;   // 12,24,36,49

    for (int bin = bin_lo; bin < bin_hi; ++bin) {
        const int ph = bin / POOLED;
        const int pw = bin - ph * POOLED;

        const int4 cy0 = coord[2 * ph + 0];
        const int4 cy1 = coord[2 * ph + 1];
        const int4 cx0 = coord[14 + 2 * pw + 0];
        const int4 cx1 = coord[14 + 2 * pw + 1];

        const float fy0 = __int_as_float(cy0.z);
        const float fy1 = __int_as_float(cy1.z);
        const float fx0 = __int_as_float(cx0.z);
        const float fx1 = __int_as_float(cx1.z);

        const float m00 = (cy0.w & cx0.w) ? 1.0f : 0.0f;  // sample validity
        const float m01 = (cy0.w & cx1.w) ? 1.0f : 0.0f;
        const float m10 = (cy1.w & cx0.w) ? 1.0f : 0.0f;
        const float m11 = (cy1.w & cx1.w) ? 1.0f : 0.0f;

        const float wyl0 = 0.5f - fy0, wyh0 = fy0;   // 0.5-scaled bases
        const float wyl1 = 0.5f - fy1, wyh1 = fy1;
        const float wxl0 = 0.5f - fx0, wxh0 = fx0;
        const float wxl1 = 0.5f - fx1, wxh1 = fx1;

        int   pix[16];
        float wgt[16];
        // sample (y0,x0)
        pix[ 0] = cy0.x + cx0.x;  wgt[ 0] = wyl0 * wxl0 * m00;
        pix[ 1] = cy0.x + cx0.y;  wgt[ 1] = wyl0 * wxh0 * m00;
        pix[ 2] = cy0.y + cx0.x;  wgt[ 2] = wyh0 * wxl0 * m00;
        pix[ 3] = cy0.y + cx0.y;  wgt[ 3] = wyh0 * wxh0 * m00;
        // sample (y0,x1)
        pix[ 4] = cy0.x + cx1.x;  wgt[ 4] = wyl0 * wxl1 * m01;
        pix[ 5] = cy0.x + cx1.y;  wgt[ 5] = wyl0 * wxh1 * m01;
        pix[ 6] = cy0.y + cx1.x;  wgt[ 6] = wyh0 * wxl1 * m01;
        pix[ 7] = cy0.y + cx1.y;  wgt[ 7] = wyh0 * wxh1 * m01;
        // sample (y1,x0)
        pix[ 8] = cy1.x + cx0.x;  wgt[ 8] = wyl1 * wxl0 * m10;
        pix[ 9] = cy1.x + cx0.y;  wgt[ 9] = wyl1 * wxh0 * m10;
        pix[10] = cy1.y + cx0.x;  wgt[10] = wyh1 * wxl0 * m10;
        pix[11] = cy1.y + cx0.y;  wgt[11] = wyh1 * wxh0 * m10;
        // sample (y1,x1)
        pix[12] = cy1.x + cx1.x;  wgt[12] = wyl1 * wxl1 * m11;
        pix[13] = cy1.x + cx1.y;  wgt[13] = wyl1 * wxh1 * m11;
        pix[14] = cy1.y + cx1.x;  wgt[14] = wyh1 * wxl1 * m11;
        pix[15] = cy1.y + cx1.y;  wgt[15] = wyh1 * wxh1 * m11;

        // 16 independent coalesced dword gathers, L1-bypass (nt), all issued
        // before any use
        uint v[16];
        #pragma unroll
        for (int k = 0; k < 16; ++k)
            v[k] = __builtin_nontemporal_load(&fb[(size_t)pix[k] * (C_ / 2)]);

        __half2 acc = __float2half2_rn(0.f);
        #pragma unroll
        for (int k = 0; k < 16; ++k)
            acc = __hfma2(__float2half2_rn(wgt[k]), *(const __half2*)&v[k], acc);

        // lane's final half2 -> LDS (bank = lane%32, 2-way for wave64: free)
        *(__half2*)&lds_out[bin * BST + 2 * lane] = acc;
    }

    __syncthreads();

    // Contiguous 128*49-float output slice: out + n*12544 + ch0*49.
    float* obase = out + (size_t)n * (C_ * PP2) + (size_t)ch0 * PP2;
    float4* o4 = (float4*)obase;
    for (int i = t; i < (CB * PP2) / 4; i += 256) {   // 1568 float4
        const int l0 = i * 4;
        float4 v;
        #pragma unroll
        for (int j = 0; j < 4; ++j) {
            const int l  = l0 + j;
            const int c  = l / PP2;          // local channel 0..127
            const int bn = l - c * PP2;
            ((float*)&v)[j] = __half2float(lds_out[bn * BST + c]);
        }
        o4[i] = v;
    }
}

// ---------------- Fallback (NCHW direct, fp32) ------------------------------
__global__ __launch_bounds__(256)
void roi_align_kernel(const float* __restrict__ rois,
                      const float* __restrict__ feat,
                      const int* __restrict__ stride_ptr,
                      int B, int C, int H, int W, int N,
                      float* __restrict__ out) {
    const int total = N * C * POOLED * POOLED;
    int idx = blockIdx.x * blockDim.x + threadIdx.x;
    if (idx >= total) return;

    const float scale = 1.0f / (float)stride_ptr[0];

    int pw = idx % POOLED;
    int ph = (idx / POOLED) % POOLED;
    int c  = (idx / (POOLED * POOLED)) % C;
    int n  = idx / (POOLED * POOLED * C);

    const float* r = rois + (size_t)n * 5;
    int b = (int)r[0];
    float x1 = r[1] * scale;
    float y1 = r[2] * scale;
    float x2 = r[3] * scale;
    float y2 = r[4] * scale;
    float bin_w = fmaxf(x2 - x1, 1.0f) / (float)POOLED;
    float bin_h = fmaxf(y2 - y1, 1.0f) / (float)POOLED;

    const float* plane = feat + ((size_t)b * C + c) * (size_t)(H * W);

    float acc = 0.0f;
    #pragma unroll
    for (int sy = 0; sy < RATIO; ++sy) {
        float iy = ((float)(ph * RATIO + sy) + 0.5f) / (float)RATIO;
        float yy = y1 + iy * bin_h;
        bool vy = (yy > -1.0f) && (yy < (float)H);
        float cy = fminf(fmaxf(yy, 0.0f), (float)(H - 1));
        int y0 = (int)floorf(cy);
        if (y0 > H - 1) y0 = H - 1;
        int y1i = min(y0 + 1, H - 1);
        float fy = cy - (float)y0;
        float hy = 1.0f - fy;

        #pragma unroll
        for (int sx = 0; sx < RATIO; ++sx) {
            float ix = ((float)(pw * RATIO + sx) + 0.5f) / (float)RATIO;
            float xx = x1 + ix * bin_w;
            bool vx = (xx > -1.0f) && (xx < (float)W);
            if (!(vy && vx)) continue;
            float cx = fminf(fmaxf(xx, 0.0f), (float)(W - 1));
            int x0 = (int)floorf(cx);
            if (x0 > W - 1) x0 = W - 1;
            int x1i = min(x0 + 1, W - 1);
            float fx = cx - (float)x0;
            float hx = 1.0f - fx;

            float v00 = plane[y0  * W + x0 ];
            float v01 = plane[y0  * W + x1i];
            float v10 = plane[y1i * W + x0 ];
            float v11 = plane[y1i * W + x1i];

            acc += hy * hx * v00 + hy * fx * v01 + fy * hx * v10 + fy * fx * v11;
        }
    }

    out[idx] = acc * 0.25f;
}

extern "C" void kernel_launch(void* const* d_in, const int* in_sizes, int n_in,
                              void* d_out, int out_size, void* d_ws, size_t ws_size,
                              hipStream_t stream) {
    const float* rois = (const float*)d_in[0];
    const float* feat = (const float*)d_in[1];
    const int* stride_ptr = (const int*)d_in[2];

    const int N = in_sizes[0] / 5;
    const int B = in_sizes[1] / (C_ * P_);
    float* out = (float*)d_out;

    const size_t need = (size_t)B * P_ * C_ * sizeof(__half);
    if (ws_size >= need) {
        __half* featT = (__half*)d_ws;
        dim3 tgrid(P_ / TP, C_ / TC, B);
        nchw_to_nhwc_h<<<tgrid, 256, 0, stream>>>(feat, featT);

        roi_align_nhwc_h<<<N * BPR, 256, 0, stream>>>(rois, featT, stride_ptr,
                                                      out, N);
    } else {
        const int total = N * C_ * POOLED * POOLED;
        const int block = 256;
        const int grid = (total + block - 1) / block;
        roi_align_kernel<<<grid, block, 0, stream>>>(rois, feat, stride_ptr,
                                                     B, C_, H_, W_, N, out);
    }
}

// Round 8
// 162.828 us; speedup vs baseline: 1.2469x; 1.1808x over previous
//
#include <hip/hip_runtime.h>
#include <hip/hip_fp16.h>

#define POOLED 7
#define RATIO 2

constexpr int C_ = 256;
constexpr int H_ = 192;
constexpr int W_ = 192;
constexpr int P_ = H_ * W_;           // pixels per plane
constexpr int PP2 = POOLED * POOLED;  // 49

// ---------------- NCHW fp32 -> NHWC fp16 transpose -------------------------
constexpr int TC = 32;
constexpr int TP = 128;
constexpr int TPAD = TP + 1;

__global__ __launch_bounds__(256)
void nchw_to_nhwc_h(const float* __restrict__ in, __half* __restrict__ outT) {
    __shared__ float tile[TC][TPAD];
    const int b  = blockIdx.z;
    const int p0 = blockIdx.x * TP;
    const int c0 = blockIdx.y * TC;
    const float* src = in   + (size_t)b * C_ * P_;
    __half*      dst = outT + (size_t)b * P_ * C_;

    const int t = threadIdx.x;

    #pragma unroll
    for (int k = 0; k < 4; ++k) {
        const int q  = t + 256 * k;
        const int c  = q >> 5;
        const int pv = q & 31;
        const float4 v = *(const float4*)&src[(size_t)(c0 + c) * P_ + p0 + 4 * pv];
        tile[c][4 * pv + 0] = v.x;
        tile[c][4 * pv + 1] = v.y;
        tile[c][4 * pv + 2] = v.z;
        tile[c][4 * pv + 3] = v.w;
    }
    __syncthreads();

    #pragma unroll
    for (int k = 0; k < 2; ++k) {
        const int q  = t + 256 * k;
        const int p  = q >> 2;
        const int c8 = (q & 3) * 8;
        union { __half h[8]; float4 f; } u;
        #pragma unroll
        for (int i = 0; i < 8; ++i) u.h[i] = __float2half(tile[c8 + i][p]);
        *(float4*)&dst[(size_t)(p0 + p) * C_ + c0 + c8] = u.f;
    }
}

// ---------------- RoIAlign on NHWC fp16 ------------------------------------
// Round-8: VALU-co-bound theory. R7 (nt) proved time ~ post-L1 line-request
// count (L1 bypass -> +50% requests -> +50% time); R3 proved tier-insensitive;
// R0/R2/R5 proved shape/MLP-insensitive; R6 proved explicit dedup net-loses.
// Remaining un-isolated axis: VALU (est. ~60% busy at R5's 44us -> co-bound).
// Change vs R5 (nt reverted): hoist per-bin (pix, wgt) into LDS tables,
// computed ONCE per block (784 entries / 256 threads, ~30 ops/thread vs ~720
// recomputed per-wave before). Inner loop: 8 broadcast ds_read_b128 (uniform
// addr, conflict-free) + 16 gathers + 16 pk_fma. Gathers byte-identical to R5.
constexpr int CB  = 128;              // channels per block
constexpr int BPR = C_ / CB;          // 2 blocks per ROI
constexpr int BST = CB + 2;           // 130 halves

__global__ __launch_bounds__(256, 4)
void roi_align_nhwc_h(const float* __restrict__ rois,
                      const __half* __restrict__ featT,   // (B,H,W,C) fp16
                      const int* __restrict__ stride_ptr,
                      float* __restrict__ out, int N) {
    __shared__ __half lds_out[PP2 * BST];  // 12740 B
    __shared__ int4 coord[28];             // [0..13]=y {lo*W, hi*W, frac*0.5, valid}
                                           // [14..27]=x {lo, hi, frac*0.5, valid}
    __shared__ int    pixT[PP2 * 16];      // 3136 B  per-bin pixel offsets
    __shared__ __half2 wgtT[PP2 * 16];     // 3136 B  per-bin half2 weights

    const int blk  = blockIdx.x;
    const int n    = blk >> 1;           // ROI index
    const int ch0  = (blk & 1) * CB;     // channel half
    const int t    = threadIdx.x;
    const int lane = t & 63;
    const int wave = t >> 6;             // 0..3

    const float scale = 1.0f / (float)stride_ptr[0];
    const float* r = rois + (size_t)n * 5;
    const int   b   = (int)r[0];
    const float rx1 = r[1] * scale;
    const float ry1 = r[2] * scale;
    const float rx2 = r[3] * scale;
    const float ry2 = r[4] * scale;
    const float bin_w = fmaxf(rx2 - rx1, 1.0f) * (1.0f / (float)POOLED);
    const float bin_h = fmaxf(ry2 - ry1, 1.0f) * (1.0f / (float)POOLED);

    if (t < 28) {
        const bool  isY   = t < 14;
        const int   s     = isY ? t : t - 14;
        const float start = isY ? ry1 : rx1;
        const float bsz   = isY ? bin_h : bin_w;
        const int   size  = isY ? H_ : W_;
        const float cc0   = start + ((float)s + 0.5f) * 0.5f * bsz;
        const bool  valid = (cc0 > -1.0f) && (cc0 < (float)size);
        float cc = fminf(fmaxf(cc0, 0.0f), (float)(size - 1));
        int lo = (int)floorf(cc);
        if (lo > size - 1) lo = size - 1;
        const int hi = min(lo + 1, size - 1);
        const float frac = (cc - (float)lo) * 0.5f;   // fold mean/4 (x*y halves)
        int4 e;
        e.x = isY ? lo * W_ : lo;
        e.y = isY ? hi * W_ : hi;
        e.z = __float_as_int(frac);
        e.w = valid ? 1 : 0;
        coord[t] = e;
    }
    __syncthreads();

    // ---- per-bin (pix, wgt) table: 784 entries, computed once per block ----
    // entry e: bin = e>>4; k = e&15 = s*4 + c, s = sample (sy,sx), c = corner.
    for (int e = t; e < PP2 * 16; e += 256) {
        const int bin = e >> 4;
        const int k   = e & 15;
        const int ph  = bin / POOLED;
        const int pw  = bin - ph * POOLED;
        const int s   = k >> 2;           // sample: sy=s>>1, sx=s&1
        const int c   = k & 3;            // corner: ysel=c>>1, xsel=c&1
        const int4 cy = coord[2 * ph + (s >> 1)];
        const int4 cx = coord[14 + 2 * pw + (s & 1)];
        const float fy = __int_as_float(cy.z);
        const float fx = __int_as_float(cx.z);
        const float wy = (c >> 1) ? fy : 0.5f - fy;
        const float wx = (c & 1)  ? fx : 0.5f - fx;
        const float m  = (cy.w & cx.w) ? 1.0f : 0.0f;
        pixT[e] = ((c >> 1) ? cy.y : cy.x) + ((c & 1) ? cx.y : cx.x);
        wgtT[e] = __float2half2_rn(wy * wx * m);
    }
    __syncthreads();

    // lane's dword (= half2 = 2 channels) within each pixel's 512B record
    const uint* fb = (const uint*)featT + (size_t)b * P_ * (C_ / 2)
                                        + (ch0 >> 1) + lane;

    const int bin_lo = (wave * PP2) >> 2;         // 0,12,24,36
    const int bin_hi = ((wave + 1) * PP2) >> 2;   // 12,24,36,49

    for (int bin = bin_lo; bin < bin_hi; ++bin) {
        // broadcast table reads (uniform address across lanes: conflict-free)
        int  pix[16];
        uint wg [16];
        #pragma unroll
        for (int q = 0; q < 4; ++q) {
            ((int4*)pix)[q] = ((const int4*)&pixT[bin * 16])[q];
            ((int4*)wg )[q] = ((const int4*)&wgtT[bin * 16])[q];
        }

        // 16 independent coalesced dword gathers — all issued before any use
        uint v[16];
        #pragma unroll
        for (int k = 0; k < 16; ++k)
            v[k] = fb[(size_t)pix[k] * (C_ / 2)];

        __half2 acc = __float2half2_rn(0.f);
        #pragma unroll
        for (int k = 0; k < 16; ++k)
            acc = __hfma2(*(const __half2*)&wg[k], *(const __half2*)&v[k], acc);

        // lane's final half2 -> LDS (bank = lane%32, 2-way for wave64: free)
        *(__half2*)&lds_out[bin * BST + 2 * lane] = acc;
    }

    __syncthreads();

    // Contiguous 128*49-float output slice: out + n*12544 + ch0*49.
    float* obase = out + (size_t)n * (C_ * PP2) + (size_t)ch0 * PP2;
    float4* o4 = (float4*)obase;
    for (int i = t; i < (CB * PP2) / 4; i += 256) {   // 1568 float4
        const int l0 = i * 4;
        float4 v;
        #pragma unroll
        for (int j = 0; j < 4; ++j) {
            const int l  = l0 + j;
            const int c  = l / PP2;          // local channel 0..127
            const int bn = l - c * PP2;
            ((float*)&v)[j] = __half2float(lds_out[bn * BST + c]);
        }
        o4[i] = v;
    }
}

// ---------------- Fallback (NCHW direct, fp32) ------------------------------
__global__ __launch_bounds__(256)
void roi_align_kernel(const float* __restrict__ rois,
                      const float* __restrict__ feat,
                      const int* __restrict__ stride_ptr,
                      int B, int C, int H, int W, int N,
                      float* __restrict__ out) {
    const int total = N * C * POOLED * POOLED;
    int idx = blockIdx.x * blockDim.x + threadIdx.x;
    if (idx >= total) return;

    const float scale = 1.0f / (float)stride_ptr[0];

    int pw = idx % POOLED;
    int ph = (idx / POOLED) % POOLED;
    int c  = (idx / (POOLED * POOLED)) % C;
    int n  = idx / (POOLED * POOLED * C);

    const float* r = rois + (size_t)n * 5;
    int b = (int)r[0];
    float x1 = r[1] * scale;
    float y1 = r[2] * scale;
    float x2 = r[3] * scale;
    float y2 = r[4] * scale;
    float bin_w = fmaxf(x2 - x1, 1.0f) / (float)POOLED;
    float bin_h = fmaxf(y2 - y1, 1.0f) / (float)POOLED;

    const float* plane = feat + ((size_t)b * C + c) * (size_t)(H * W);

    float acc = 0.0f;
    #pragma unroll
    for (int sy = 0; sy < RATIO; ++sy) {
        float iy = ((float)(ph * RATIO + sy) + 0.5f) / (float)RATIO;
        float yy = y1 + iy * bin_h;
        bool vy = (yy > -1.0f) && (yy < (float)H);
        float cy = fminf(fmaxf(yy, 0.0f), (float)(H - 1));
        int y0 = (int)floorf(cy);
        if (y0 > H - 1) y0 = H - 1;
        int y1i = min(y0 + 1, H - 1);
        float fy = cy - (float)y0;
        float hy = 1.0f - fy;

        #pragma unroll
        for (int sx = 0; sx < RATIO; ++sx) {
            float ix = ((float)(pw * RATIO + sx) + 0.5f) / (float)RATIO;
            float xx = x1 + ix * bin_w;
            bool vx = (xx > -1.0f) && (xx < (float)W);
            if (!(vy && vx)) continue;
            float cx = fminf(fmaxf(xx, 0.0f), (float)(W - 1));
            int x0 = (int)floorf(cx);
            if (x0 > W - 1) x0 = W - 1;
            int x1i = min(x0 + 1, W - 1);
            float fx = cx - (float)x0;
            float hx = 1.0f - fx;

            float v00 = plane[y0  * W + x0 ];
            float v01 = plane[y0  * W + x1i];
            float v10 = plane[y1i * W + x0 ];
            float v11 = plane[y1i * W + x1i];

            acc += hy * hx * v00 + hy * fx * v01 + fy * hx * v10 + fy * fx * v11;
        }
    }

    out[idx] = acc * 0.25f;
}

extern "C" void kernel_launch(void* const* d_in, const int* in_sizes, int n_in,
                              void* d_out, int out_size, void* d_ws, size_t ws_size,
                              hipStream_t stream) {
    const float* rois = (const float*)d_in[0];
    const float* feat = (const float*)d_in[1];
    const int* stride_ptr = (const int*)d_in[2];

    const int N = in_sizes[0] / 5;
    const int B = in_sizes[1] / (C_ * P_);
    float* out = (float*)d_out;

    const size_t need = (size_t)B * P_ * C_ * sizeof(__half);
    if (ws_size >= need) {
        __half* featT = (__half*)d_ws;
        dim3 tgrid(P_ / TP, C_ / TC, B);
        nchw_to_nhwc_h<<<tgrid, 256, 0, stream>>>(feat, featT);

        roi_align_nhwc_h<<<N * BPR, 256, 0, stream>>>(rois, featT, stride_ptr,
                                                      out, N);
    } else {
        const int total = N * C_ * POOLED * POOLED;
        const int block = 256;
        const int grid = (total + block - 1) / block;
        roi_align_kernel<<<grid, block, 0, stream>>>(rois, feat, stride_ptr,
                                                     B, C_, H_, W_, N, out);
    }
}